// Round 1
// baseline (18149.562 us; speedup 1.0000x reference)
//
#include <hip/hip_runtime.h>

// GRU forward, B=64 S=512 I=512 H=1024. fp32 I/O, bf16 MFMA internals.
// Round 3: single persistent kernel for all 512 steps.
//  - 512 blocks x 64 threads (1 wave), 2 blocks/CU (LDS-bound: 64 KiB each).
//  - block (gate,bg,rowg): gate1 = r-producer; gate0 = z (in regs) + h-tile.
//  - per-bg flag arrays (release-store / acquire-spin), no kernel boundaries,
//    no global barrier: the 4 batch-group chains run fully independently.
//  - U slices staged once into LDS with 16B-chunk XOR swizzle (conflict-free
//    ds_read_b128); W/x loops run before the flag wait (latency-hidden).
//  - h_bf16 double-buffered (ping-pong on t); h_f32/rh single-buffer safe by
//    the flag dependency chain.

#define B_ 64
#define S_ 512
#define I_ 512
#define H_ 1024
#define HB_ (B_ * H_)

typedef short short8 __attribute__((ext_vector_type(8)));
typedef float floatx4 __attribute__((ext_vector_type(4)));

__device__ inline floatx4 mfma16(short8 a, short8 b, floatx4 c) {
    return __builtin_amdgcn_mfma_f32_16x16x32_bf16(a, b, c, 0, 0, 0);
}

// fp32 -> bf16 bits, round-to-nearest-even (inputs are finite)
__device__ inline short f2bf(float f) {
    union { float f; unsigned u; } v; v.f = f;
    unsigned r = (v.u + 0x7FFFu + ((v.u >> 16) & 1u)) >> 16;
    return (short)r;
}

// ---- bulk fp32 -> bf16 conversion, 8 elements/thread ----
__global__ __launch_bounds__(256) void cvt8k(const float* __restrict__ src,
                                             short* __restrict__ dst, int n8) {
    int i = blockIdx.x * 256 + threadIdx.x;
    if (i >= n8) return;
    const float4* p = reinterpret_cast<const float4*>(src) + (size_t)i * 2;
    float4 f0 = p[0], f1 = p[1];
    short8 o;
    o[0] = f2bf(f0.x); o[1] = f2bf(f0.y); o[2] = f2bf(f0.z); o[3] = f2bf(f0.w);
    o[4] = f2bf(f1.x); o[5] = f2bf(f1.y); o[6] = f2bf(f1.z); o[7] = f2bf(f1.w);
    reinterpret_cast<short8*>(dst)[i] = o;
}

// ---- init h state from h_0 and zero the sync flags ----
__global__ __launch_bounds__(256) void gru_init(const float* __restrict__ h0,
                                                float* __restrict__ h_f32,
                                                short* __restrict__ h_b,
                                                int* __restrict__ flags) {
    int i = blockIdx.x * 256 + threadIdx.x;
    if (i < 512) flags[i] = 0;
    if (i < HB_) {
        float v = h0[i];
        h_f32[i] = v;
        h_b[i] = f2bf(v);   // buffer 0 holds h(0)
    }
}

// A-fragment from fp32 x with on-the-fly bf16 conversion
__device__ inline short8 loadA_f32(const float* p) {
    const float4* q = reinterpret_cast<const float4*>(p);
    float4 f0 = q[0], f1 = q[1];
    short8 a;
    a[0] = f2bf(f0.x); a[1] = f2bf(f0.y); a[2] = f2bf(f0.z); a[3] = f2bf(f0.w);
    a[4] = f2bf(f1.x); a[5] = f2bf(f1.y); a[6] = f2bf(f1.z); a[7] = f2bf(f1.w);
    return a;
}

// lane i watches flags[i]; exits when all 64 flags >= target. Acquire fence
// afterwards makes producers' data stores visible (cross-XCD).
__device__ inline void wait64(const int* f, int target) {
    const int* p = f + (threadIdx.x & 63);
    while (__hip_atomic_load(p, __ATOMIC_RELAXED, __HIP_MEMORY_SCOPE_AGENT) < target)
        __builtin_amdgcn_s_sleep(2);
    __builtin_amdgcn_fence(__ATOMIC_ACQUIRE, "agent");
}

// ---- persistent GRU kernel: all S_ steps in one launch ----
// grid 512 = 2 gates x 4 batch-groups x 64 row-groups, 64 threads (1 wave).
// MFMA 16x16x32 bf16 NT conventions copied verbatim from the verified round-2
// kernel: A row = lane&15, k = quad*8+e; B row (=output col j) = lane&15;
// D: n = lane&15, m = quad*4+reg.
template <bool XB>
__global__ __launch_bounds__(64) void gru_persist(
    const float* __restrict__ x, const short* __restrict__ xb,
    const short* __restrict__ Wzb, const float* __restrict__ bz, const short* __restrict__ Uzb,
    const short* __restrict__ Wrb, const float* __restrict__ br, const short* __restrict__ Urb,
    const short* __restrict__ Whb, const float* __restrict__ bh, const short* __restrict__ Uhb,
    float* __restrict__ h_f32, short* __restrict__ h_b, short* __restrict__ rh,
    int* __restrict__ flagh, int* __restrict__ flagr, float* __restrict__ out)
{
    // 64 KiB: [0..2048) own-gate U slice (Uz or Ur), [2048..4096) Uh (gate0 only)
    __shared__ short8 Ulds[4096];

    const int blk  = blockIdx.x;
    const int gate = blk & 1;          // 0 = z+h block, 1 = r block
    const int bg   = (blk >> 1) & 3;   // batch group of 16
    const int rowg = blk >> 3;         // 64 output row groups of 16
    const int lane = threadIdx.x;
    const int m16  = lane & 15, quad = lane >> 4;
    const int bBase = bg * 16, jBase = rowg * 16;
    const int j = jBase + m16;

    // ---- stage U slice(s) into LDS once; 16B-chunk XOR swizzle:
    // chunk(row,col) -> index row*128 + (col ^ (row&7)); makes the stride-2048B
    // column reads land 8 lanes/slot -> 2 lanes/bank (free, m136).
    {
        const short* s0 = (gate ? Urb : Uzb) + (size_t)jBase * H_;
        for (int c = lane; c < 2048; c += 64) {
            int row = c >> 7, col = c & 127;
            Ulds[row * 128 + (col ^ (row & 7))] = *(const short8*)(s0 + row * H_ + col * 8);
        }
        if (!gate) {
            const short* s1 = Uhb + (size_t)jBase * H_;
            for (int c = lane; c < 2048; c += 64) {
                int row = c >> 7, col = c & 127;
                Ulds[2048 + row * 128 + (col ^ (row & 7))] = *(const short8*)(s1 + row * H_ + col * 8);
            }
        }
    }
    __syncthreads();

    // per-lane constant LDS read base (short8 units) + the bit-6 part of the XOR
    const int ub  = m16 * 128 + (quad ^ (m16 & 3));
    const int itf = (m16 >> 2) & 1;

    const float bv0 = gate ? br[j] : bz[j];
    const float bvh = gate ? 0.f : bh[j];
    const short8* wz = reinterpret_cast<const short8*>((gate ? Wrb : Wzb) + (size_t)j * I_) + quad;
    const short8* wh = reinterpret_cast<const short8*>(Whb + (size_t)j * I_) + quad;

    const int* fh = flagh + bg * 64;
    const int* fr = flagr + bg * 64;
    int* myfr = flagr + bg * 64 + rowg;
    int* myfh = flagh + bg * 64 + rowg;

    for (int t = 0; t < S_; ++t) {
        floatx4 a0 = {0.f, 0.f, 0.f, 0.f}, a1 = {0.f, 0.f, 0.f, 0.f};
        floatx4 c0 = {0.f, 0.f, 0.f, 0.f}, c1 = {0.f, 0.f, 0.f, 0.f};

        // ---- x@W part: no dependence on h -> runs BEFORE the flag wait ----
        const size_t xrow = ((size_t)(bBase + m16) * S_ + t) * I_;
        if (XB) {
            const short8* ax = reinterpret_cast<const short8*>(xb + xrow) + quad;
            if (!gate) {
#pragma unroll
                for (int it = 0; it < I_ / 32; it += 2) {
                    short8 A0 = ax[it * 4], A1 = ax[(it + 1) * 4];
                    a0 = mfma16(A0, wz[it * 4], a0);
                    a1 = mfma16(A1, wz[(it + 1) * 4], a1);
                    c0 = mfma16(A0, wh[it * 4], c0);
                    c1 = mfma16(A1, wh[(it + 1) * 4], c1);
                }
            } else {
#pragma unroll
                for (int it = 0; it < I_ / 32; it += 2) {
                    a0 = mfma16(ax[it * 4], wz[it * 4], a0);
                    a1 = mfma16(ax[(it + 1) * 4], wz[(it + 1) * 4], a1);
                }
            }
        } else {
            const float* axf = x + xrow + quad * 8;
            if (!gate) {
#pragma unroll
                for (int it = 0; it < I_ / 32; it += 2) {
                    short8 A0 = loadA_f32(axf + it * 32);
                    short8 A1 = loadA_f32(axf + (it + 1) * 32);
                    a0 = mfma16(A0, wz[it * 4], a0);
                    a1 = mfma16(A1, wz[(it + 1) * 4], a1);
                    c0 = mfma16(A0, wh[it * 4], c0);
                    c1 = mfma16(A1, wh[(it + 1) * 4], c1);
                }
            } else {
#pragma unroll
                for (int it = 0; it < I_ / 32; it += 2) {
                    a0 = mfma16(loadA_f32(axf + it * 32), wz[it * 4], a0);
                    a1 = mfma16(loadA_f32(axf + (it + 1) * 32), wz[(it + 1) * 4], a1);
                }
            }
        }

        // ---- wait for h(t) (trivially true at t=0: flags zeroed, h0 staged) ----
        wait64(fh, t);

        // ---- z/r recurrent GEMM: A = h(t) bf16 (ping-pong buf), B = U from LDS ----
        const short8* ah = reinterpret_cast<const short8*>(
            h_b + (size_t)(t & 1) * HB_ + (size_t)(bBase + m16) * H_) + quad;
#pragma unroll
        for (int it = 0; it < H_ / 32; it += 2) {
            a0 = mfma16(ah[it * 4],       Ulds[ub + ((it ^ itf) << 2)],       a0);
            a1 = mfma16(ah[(it + 1) * 4], Ulds[ub + (((it + 1) ^ itf) << 2)], a1);
        }
        floatx4 acc = a0 + a1;

        if (gate) {
            // ---- r epilogue: rh = sigmoid(pre) * h(t), publish ----
#pragma unroll
            for (int r4 = 0; r4 < 4; ++r4) {
                int b = bBase + quad * 4 + r4;
                float g = 1.f / (1.f + __expf(-(acc[r4] + bv0)));
                size_t idx = (size_t)b * H_ + j;
                rh[idx] = f2bf(g * h_f32[idx]);
            }
            __builtin_amdgcn_fence(__ATOMIC_RELEASE, "agent");
            if (lane == 0)
                __hip_atomic_store(myfr, t + 1, __ATOMIC_RELAXED, __HIP_MEMORY_SCOPE_AGENT);
        } else {
            // ---- z stays in registers ----
            float zz[4];
#pragma unroll
            for (int r4 = 0; r4 < 4; ++r4)
                zz[r4] = 1.f / (1.f + __expf(-(acc[r4] + bv0)));

            // ---- wait for the full rh(t) row, then h_hat GEMM ----
            wait64(fr, t + 1);
            const short8* ar = reinterpret_cast<const short8*>(
                rh + (size_t)(bBase + m16) * H_) + quad;
#pragma unroll
            for (int it = 0; it < H_ / 32; it += 2) {
                c0 = mfma16(ar[it * 4],       Ulds[2048 + ub + ((it ^ itf) << 2)],       c0);
                c1 = mfma16(ar[(it + 1) * 4], Ulds[2048 + ub + (((it + 1) ^ itf) << 2)], c1);
            }
            floatx4 acch = c0 + c1;

            // ---- h update epilogue ----
#pragma unroll
            for (int r4 = 0; r4 < 4; ++r4) {
                int b = bBase + quad * 4 + r4;
                size_t idx = (size_t)b * H_ + j;
                float hh = tanhf(acch[r4] + bvh);
                float hv = h_f32[idx];
                float hn = fmaf(zz[r4], hh - hv, hv);   // (1-z)h + z*h_hat
                h_f32[idx] = hn;
                h_b[(size_t)((t + 1) & 1) * HB_ + idx] = f2bf(hn);
                out[(size_t)b * (S_ * H_) + (size_t)t * H_ + j] = hn;
                if (t == S_ - 1) out[(size_t)(B_ * S_ * H_) + idx] = hn;
            }
            __builtin_amdgcn_fence(__ATOMIC_RELEASE, "agent");
            if (lane == 0)
                __hip_atomic_store(myfh, t + 1, __ATOMIC_RELAXED, __HIP_MEMORY_SCOPE_AGENT);
        }
    }
}

extern "C" void kernel_launch(void* const* d_in, const int* in_sizes, int n_in,
                              void* d_out, int out_size, void* d_ws, size_t ws_size,
                              hipStream_t stream) {
    const float* x  = (const float*)d_in[0];
    const float* h0 = (const float*)d_in[1];
    const float* Wz = (const float*)d_in[2];
    const float* bz = (const float*)d_in[3];
    const float* Uz = (const float*)d_in[4];
    const float* Wr = (const float*)d_in[5];
    const float* br = (const float*)d_in[6];
    const float* Ur = (const float*)d_in[7];
    const float* Wh = (const float*)d_in[8];
    const float* bh = (const float*)d_in[9];
    const float* Uh = (const float*)d_in[10];
    float* out = (float*)d_out;

    const int WI = H_ * I_;                  // 524288 elems per W
    const int UU = H_ * H_;                  // 1048576 elems per U
    const size_t XN = (size_t)B_ * S_ * I_;  // 16777216 elems

    // ws layout: h_f32 | h_bf16[2] | rh | flags[512] | Wz Wr Wh (bf16) | Uz Ur Uh (bf16) | [x_b]
    char* w = (char*)d_ws;
    float* h_f32 = (float*)w;            w += (size_t)HB_ * 4;
    short* h_b   = (short*)w;            w += (size_t)HB_ * 2 * 2;   // double buffer
    short* rhb   = (short*)w;            w += (size_t)HB_ * 2;
    int*   flags = (int*)w;              w += 512 * 4;
    short* Wzb   = (short*)w;            w += (size_t)WI * 2;
    short* Wrb   = (short*)w;            w += (size_t)WI * 2;
    short* Whb   = (short*)w;            w += (size_t)WI * 2;
    short* Uzb   = (short*)w;            w += (size_t)UU * 2;
    short* Urb   = (short*)w;            w += (size_t)UU * 2;
    short* Uhb   = (short*)w;            w += (size_t)UU * 2;
    size_t base_need = (size_t)(w - (char*)d_ws);
    bool XB = ws_size >= base_need + XN * 2;
    short* xb = (short*)w;

    int* flagh = flags;          // [4][64]
    int* flagr = flags + 256;    // [4][64]

    gru_init<<<dim3(HB_ / 256), 256, 0, stream>>>(h0, h_f32, h_b, flags);
    cvt8k<<<dim3(WI / 8 / 256), 256, 0, stream>>>(Wz, Wzb, WI / 8);
    cvt8k<<<dim3(WI / 8 / 256), 256, 0, stream>>>(Wr, Wrb, WI / 8);
    cvt8k<<<dim3(WI / 8 / 256), 256, 0, stream>>>(Wh, Whb, WI / 8);
    cvt8k<<<dim3(UU / 8 / 256), 256, 0, stream>>>(Uz, Uzb, UU / 8);
    cvt8k<<<dim3(UU / 8 / 256), 256, 0, stream>>>(Ur, Urb, UU / 8);
    cvt8k<<<dim3(UU / 8 / 256), 256, 0, stream>>>(Uh, Uhb, UU / 8);
    if (XB)
        cvt8k<<<dim3((int)(XN / 8 / 256)), 256, 0, stream>>>(x, xb, (int)(XN / 8));

    if (XB)
        gru_persist<true><<<dim3(512), 64, 0, stream>>>(
            x, xb, Wzb, bz, Uzb, Wrb, br, Urb, Whb, bh, Uhb,
            h_f32, h_b, rhb, flagh, flagr, out);
    else
        gru_persist<false><<<dim3(512), 64, 0, stream>>>(
            x, xb, Wzb, bz, Uzb, Wrb, br, Urb, Whb, bh, Uhb,
            h_f32, h_b, rhb, flagh, flagr, out);
}

// Round 2
// 4697.818 us; speedup vs baseline: 3.8634x; 3.8634x over previous
//
#include <hip/hip_runtime.h>

// GRU forward, B=64 S=512 I=512 H=1024. fp32 I/O, bf16 MFMA internals.
// Round 4: persistent kernel, FENCELESS cross-block sync.
//  - Round-3's agent fences (buffer_inv / buffer_wbl2 per hop) were the 17us/hop
//    cost. Replaced with per-op device-coherent traffic:
//      stores: __hip_atomic_store(RELAXED, AGENT)  (write-through to IC, no fence)
//      loads : inline-asm global_load_dwordx4 sc0 sc1, batched, ONE vmcnt(0)
//              + sched_barrier(0) (rule #18) per row-block.
//    release = s_waitcnt vmcnt(0) then relaxed flag store; acquire = nothing.
//  - h_f32 master lives in gate-0 REGISTERS (stationary tile); published copy
//    only for gate-1's rh epilogue.
//  - x/W/U plain loads now stay L2-resident (no cache invalidation anywhere).
//  - Everything else (block decomposition, LDS-staged swizzled U, flags,
//    double-buffered h_bf16) unchanged from the round-3 structure that passed.

#define B_ 64
#define S_ 512
#define I_ 512
#define H_ 1024
#define HB_ (B_ * H_)

typedef short short8 __attribute__((ext_vector_type(8)));
typedef float floatx4 __attribute__((ext_vector_type(4)));

__device__ inline floatx4 mfma16(short8 a, short8 b, floatx4 c) {
    return __builtin_amdgcn_mfma_f32_16x16x32_bf16(a, b, c, 0, 0, 0);
}

// fp32 -> bf16 bits, round-to-nearest-even (inputs are finite)
__device__ inline short f2bf(float f) {
    union { float f; unsigned u; } v; v.f = f;
    unsigned r = (v.u + 0x7FFFu + ((v.u >> 16) & 1u)) >> 16;
    return (short)r;
}

// ---- bulk fp32 -> bf16 conversion, 8 elements/thread ----
__global__ __launch_bounds__(256) void cvt8k(const float* __restrict__ src,
                                             short* __restrict__ dst, int n8) {
    int i = blockIdx.x * 256 + threadIdx.x;
    if (i >= n8) return;
    const float4* p = reinterpret_cast<const float4*>(src) + (size_t)i * 2;
    float4 f0 = p[0], f1 = p[1];
    short8 o;
    o[0] = f2bf(f0.x); o[1] = f2bf(f0.y); o[2] = f2bf(f0.z); o[3] = f2bf(f0.w);
    o[4] = f2bf(f1.x); o[5] = f2bf(f1.y); o[6] = f2bf(f1.z); o[7] = f2bf(f1.w);
    reinterpret_cast<short8*>(dst)[i] = o;
}

// ---- init h state from h_0 and zero the sync flags ----
// (kernel-boundary implicit flush makes these visible to the coherent loads
//  of gru_persist)
__global__ __launch_bounds__(256) void gru_init(const float* __restrict__ h0,
                                                float* __restrict__ h_f32,
                                                short* __restrict__ h_b,
                                                int* __restrict__ flags) {
    int i = blockIdx.x * 256 + threadIdx.x;
    if (i < 512) flags[i] = 0;
    if (i < HB_) {
        float v = h0[i];
        h_f32[i] = v;
        h_b[i] = f2bf(v);   // buffer 0 holds h(0)
    }
}

// A-fragment from fp32 x with on-the-fly bf16 conversion
__device__ inline short8 loadA_f32(const float* p) {
    const float4* q = reinterpret_cast<const float4*>(p);
    float4 f0 = q[0], f1 = q[1];
    short8 a;
    a[0] = f2bf(f0.x); a[1] = f2bf(f0.y); a[2] = f2bf(f0.z); a[3] = f2bf(f0.w);
    a[4] = f2bf(f1.x); a[5] = f2bf(f1.y); a[6] = f2bf(f1.z); a[7] = f2bf(f1.w);
    return a;
}

// lane i watches flags[i]; exits when all 64 flags >= target. NO fence after:
// all communicated data is read with per-op coherent loads.
__device__ inline void wait64(const int* f, int target) {
    const int* p = f + (threadIdx.x & 63);
    while (__hip_atomic_load(p, __ATOMIC_RELAXED, __HIP_MEMORY_SCOPE_AGENT) < target)
        __builtin_amdgcn_s_sleep(1);
}

// 32 device-coherent 16B loads (bypass L1/L2 -> read at IC) with immediate
// offsets off one base, ONE vmcnt drain, then sched_barrier so the compiler
// cannot hoist consumers above the wait (guide rule #18).
__device__ inline void ld_frag32(const short* base, short8* f) {
    asm volatile(
        "global_load_dwordx4 %0, %16, off sc0 sc1\n\t"
        "global_load_dwordx4 %1, %16, off offset:64 sc0 sc1\n\t"
        "global_load_dwordx4 %2, %16, off offset:128 sc0 sc1\n\t"
        "global_load_dwordx4 %3, %16, off offset:192 sc0 sc1\n\t"
        "global_load_dwordx4 %4, %16, off offset:256 sc0 sc1\n\t"
        "global_load_dwordx4 %5, %16, off offset:320 sc0 sc1\n\t"
        "global_load_dwordx4 %6, %16, off offset:384 sc0 sc1\n\t"
        "global_load_dwordx4 %7, %16, off offset:448 sc0 sc1\n\t"
        "global_load_dwordx4 %8, %16, off offset:512 sc0 sc1\n\t"
        "global_load_dwordx4 %9, %16, off offset:576 sc0 sc1\n\t"
        "global_load_dwordx4 %10, %16, off offset:640 sc0 sc1\n\t"
        "global_load_dwordx4 %11, %16, off offset:704 sc0 sc1\n\t"
        "global_load_dwordx4 %12, %16, off offset:768 sc0 sc1\n\t"
        "global_load_dwordx4 %13, %16, off offset:832 sc0 sc1\n\t"
        "global_load_dwordx4 %14, %16, off offset:896 sc0 sc1\n\t"
        "global_load_dwordx4 %15, %16, off offset:960 sc0 sc1"
        : "=&v"(f[0]), "=&v"(f[1]), "=&v"(f[2]), "=&v"(f[3]),
          "=&v"(f[4]), "=&v"(f[5]), "=&v"(f[6]), "=&v"(f[7]),
          "=&v"(f[8]), "=&v"(f[9]), "=&v"(f[10]), "=&v"(f[11]),
          "=&v"(f[12]), "=&v"(f[13]), "=&v"(f[14]), "=&v"(f[15])
        : "v"(base)
        : "memory");
    asm volatile(
        "global_load_dwordx4 %0, %16, off offset:1024 sc0 sc1\n\t"
        "global_load_dwordx4 %1, %16, off offset:1088 sc0 sc1\n\t"
        "global_load_dwordx4 %2, %16, off offset:1152 sc0 sc1\n\t"
        "global_load_dwordx4 %3, %16, off offset:1216 sc0 sc1\n\t"
        "global_load_dwordx4 %4, %16, off offset:1280 sc0 sc1\n\t"
        "global_load_dwordx4 %5, %16, off offset:1344 sc0 sc1\n\t"
        "global_load_dwordx4 %6, %16, off offset:1408 sc0 sc1\n\t"
        "global_load_dwordx4 %7, %16, off offset:1472 sc0 sc1\n\t"
        "global_load_dwordx4 %8, %16, off offset:1536 sc0 sc1\n\t"
        "global_load_dwordx4 %9, %16, off offset:1600 sc0 sc1\n\t"
        "global_load_dwordx4 %10, %16, off offset:1664 sc0 sc1\n\t"
        "global_load_dwordx4 %11, %16, off offset:1728 sc0 sc1\n\t"
        "global_load_dwordx4 %12, %16, off offset:1792 sc0 sc1\n\t"
        "global_load_dwordx4 %13, %16, off offset:1856 sc0 sc1\n\t"
        "global_load_dwordx4 %14, %16, off offset:1920 sc0 sc1\n\t"
        "global_load_dwordx4 %15, %16, off offset:1984 sc0 sc1\n\t"
        "s_waitcnt vmcnt(0)"
        : "=&v"(f[16]), "=&v"(f[17]), "=&v"(f[18]), "=&v"(f[19]),
          "=&v"(f[20]), "=&v"(f[21]), "=&v"(f[22]), "=&v"(f[23]),
          "=&v"(f[24]), "=&v"(f[25]), "=&v"(f[26]), "=&v"(f[27]),
          "=&v"(f[28]), "=&v"(f[29]), "=&v"(f[30]), "=&v"(f[31])
        : "v"(base)
        : "memory");
    __builtin_amdgcn_sched_barrier(0);
}

// release publish: drain all outstanding stores (coherent stores retire once
// globally visible at IC), then relaxed flag store by lane 0.
__device__ inline void publish(int* flag, int val, int lane) {
    asm volatile("s_waitcnt vmcnt(0)" ::: "memory");
    if (lane == 0)
        __hip_atomic_store(flag, val, __ATOMIC_RELAXED, __HIP_MEMORY_SCOPE_AGENT);
}

template <typename T>
__device__ inline void st_coh(T* p, T v) {
    __hip_atomic_store(p, v, __ATOMIC_RELAXED, __HIP_MEMORY_SCOPE_AGENT);
}

// ---- persistent GRU kernel: all S_ steps in one launch ----
// grid 512 = 2 gates x 4 batch-groups x 64 row-groups, 64 threads (1 wave).
// MFMA 16x16x32 bf16 NT conventions (m89/m91-verified): A row = lane&15,
// k = quad*8+e; B row (= output col j) = lane&15; D: n = lane&15, m = quad*4+reg.
template <bool XB>
__global__ __launch_bounds__(64) void gru_persist(
    const float* __restrict__ x, const short* __restrict__ xb,
    const float* __restrict__ h0,
    const short* __restrict__ Wzb, const float* __restrict__ bz, const short* __restrict__ Uzb,
    const short* __restrict__ Wrb, const float* __restrict__ br, const short* __restrict__ Urb,
    const short* __restrict__ Whb, const float* __restrict__ bh, const short* __restrict__ Uhb,
    float* __restrict__ h_f32, short* __restrict__ h_b, short* __restrict__ rh,
    int* __restrict__ flagh, int* __restrict__ flagr, float* __restrict__ out)
{
    // 64 KiB: [0..2048) own-gate U slice (Uz or Ur), [2048..4096) Uh (gate0 only)
    __shared__ short8 Ulds[4096];

    const int blk  = blockIdx.x;
    const int gate = blk & 1;          // 0 = z+h block, 1 = r block
    const int bg   = (blk >> 1) & 3;   // batch group of 16
    const int rowg = blk >> 3;         // 64 output row groups of 16
    const int lane = threadIdx.x;
    const int m16  = lane & 15, quad = lane >> 4;
    const int bBase = bg * 16, jBase = rowg * 16;
    const int j = jBase + m16;

    // ---- stage U slice(s) into LDS once; 16B-chunk XOR swizzle ----
    {
        const short* s0 = (gate ? Urb : Uzb) + (size_t)jBase * H_;
        for (int c = lane; c < 2048; c += 64) {
            int row = c >> 7, col = c & 127;
            Ulds[row * 128 + (col ^ (row & 7))] = *(const short8*)(s0 + row * H_ + col * 8);
        }
        if (!gate) {
            const short* s1 = Uhb + (size_t)jBase * H_;
            for (int c = lane; c < 2048; c += 64) {
                int row = c >> 7, col = c & 127;
                Ulds[2048 + row * 128 + (col ^ (row & 7))] = *(const short8*)(s1 + row * H_ + col * 8);
            }
        }
    }
    __syncthreads();

    const int ub  = m16 * 128 + (quad ^ (m16 & 3));
    const int itf = (m16 >> 2) & 1;

    const float bv0 = gate ? br[j] : bz[j];
    const float bvh = gate ? 0.f : bh[j];
    const short8* wz = reinterpret_cast<const short8*>((gate ? Wrb : Wzb) + (size_t)j * I_) + quad;
    const short8* wh = reinterpret_cast<const short8*>(Whb + (size_t)j * I_) + quad;

    const int* fh = flagh + bg * 64;
    const int* fr = flagr + bg * 64;
    int* myfr = flagr + bg * 64 + rowg;
    int* myfh = flagh + bg * 64 + rowg;

    // gate0: f32 master copy of this block's stationary h tile, in registers.
    float hreg[4];
    if (!gate) {
#pragma unroll
        for (int r4 = 0; r4 < 4; ++r4)
            hreg[r4] = h0[(size_t)(bBase + quad * 4 + r4) * H_ + j];
    }

    short8 frag[32];

    for (int t = 0; t < S_; ++t) {
        floatx4 a0 = {0.f, 0.f, 0.f, 0.f}, a1 = {0.f, 0.f, 0.f, 0.f};
        floatx4 c0 = {0.f, 0.f, 0.f, 0.f}, c1 = {0.f, 0.f, 0.f, 0.f};

        // ---- x@W part: no dependence on h -> runs BEFORE the flag wait ----
        const size_t xrow = ((size_t)(bBase + m16) * S_ + t) * I_;
        if (XB) {
            const short8* ax = reinterpret_cast<const short8*>(xb + xrow) + quad;
            if (!gate) {
#pragma unroll
                for (int it = 0; it < I_ / 32; it += 2) {
                    short8 A0 = ax[it * 4], A1 = ax[(it + 1) * 4];
                    a0 = mfma16(A0, wz[it * 4], a0);
                    a1 = mfma16(A1, wz[(it + 1) * 4], a1);
                    c0 = mfma16(A0, wh[it * 4], c0);
                    c1 = mfma16(A1, wh[(it + 1) * 4], c1);
                }
            } else {
#pragma unroll
                for (int it = 0; it < I_ / 32; it += 2) {
                    a0 = mfma16(ax[it * 4], wz[it * 4], a0);
                    a1 = mfma16(ax[(it + 1) * 4], wz[(it + 1) * 4], a1);
                }
            }
        } else {
            const float* axf = x + xrow + quad * 8;
            if (!gate) {
#pragma unroll
                for (int it = 0; it < I_ / 32; it += 2) {
                    short8 A0 = loadA_f32(axf + it * 32);
                    short8 A1 = loadA_f32(axf + (it + 1) * 32);
                    a0 = mfma16(A0, wz[it * 4], a0);
                    a1 = mfma16(A1, wz[(it + 1) * 4], a1);
                    c0 = mfma16(A0, wh[it * 4], c0);
                    c1 = mfma16(A1, wh[(it + 1) * 4], c1);
                }
            } else {
#pragma unroll
                for (int it = 0; it < I_ / 32; it += 2) {
                    a0 = mfma16(loadA_f32(axf + it * 32), wz[it * 4], a0);
                    a1 = mfma16(loadA_f32(axf + (it + 1) * 32), wz[(it + 1) * 4], a1);
                }
            }
        }

        // ---- wait for h(t) (trivially true at t=0) ----
        wait64(fh, t);

        const short* hrow = h_b + (size_t)(t & 1) * HB_ + (size_t)(bBase + m16) * H_ + quad * 8;

        if (gate) {
            // coherent scalar h_f32 reads for the rh epilogue; issued before the
            // fragment block so their latency overlaps its drain.
            float hv[4];
#pragma unroll
            for (int r4 = 0; r4 < 4; ++r4)
                hv[r4] = __hip_atomic_load(h_f32 + (size_t)(bBase + quad * 4 + r4) * H_ + j,
                                           __ATOMIC_RELAXED, __HIP_MEMORY_SCOPE_AGENT);
            ld_frag32(hrow, frag);
#pragma unroll
            for (int it = 0; it < H_ / 32; it += 2) {
                a0 = mfma16(frag[it],     Ulds[ub + ((it ^ itf) << 2)],       a0);
                a1 = mfma16(frag[it + 1], Ulds[ub + (((it + 1) ^ itf) << 2)], a1);
            }
            floatx4 acc = a0 + a1;
#pragma unroll
            for (int r4 = 0; r4 < 4; ++r4) {
                float g = 1.f / (1.f + __expf(-(acc[r4] + bv0)));
                size_t idx = (size_t)(bBase + quad * 4 + r4) * H_ + j;
                st_coh(rh + idx, f2bf(g * hv[r4]));
            }
            publish(myfr, t + 1, lane);
        } else {
            // ---- Uz GEMM on h(t) ----
            ld_frag32(hrow, frag);
#pragma unroll
            for (int it = 0; it < H_ / 32; it += 2) {
                a0 = mfma16(frag[it],     Ulds[ub + ((it ^ itf) << 2)],       a0);
                a1 = mfma16(frag[it + 1], Ulds[ub + (((it + 1) ^ itf) << 2)], a1);
            }
            floatx4 acc = a0 + a1;
            float zz[4];
#pragma unroll
            for (int r4 = 0; r4 < 4; ++r4)
                zz[r4] = 1.f / (1.f + __expf(-(acc[r4] + bv0)));

            // ---- wait for the full rh(t) row, then Uh GEMM ----
            wait64(fr, t + 1);
            ld_frag32(rh + (size_t)(bBase + m16) * H_ + quad * 8, frag);
#pragma unroll
            for (int it = 0; it < H_ / 32; it += 2) {
                c0 = mfma16(frag[it],     Ulds[2048 + ub + ((it ^ itf) << 2)],       c0);
                c1 = mfma16(frag[it + 1], Ulds[2048 + ub + (((it + 1) ^ itf) << 2)], c1);
            }
            floatx4 acch = c0 + c1;

            // ---- h update epilogue ----
#pragma unroll
            for (int r4 = 0; r4 < 4; ++r4) {
                int b = bBase + quad * 4 + r4;
                size_t idx = (size_t)b * H_ + j;
                float hh = tanhf(acch[r4] + bvh);
                float hn = fmaf(zz[r4], hh - hreg[r4], hreg[r4]);   // (1-z)h + z*h_hat
                hreg[r4] = hn;
                st_coh(h_f32 + idx, hn);
                st_coh(h_b + (size_t)((t + 1) & 1) * HB_ + idx, f2bf(hn));
                out[(size_t)b * (S_ * H_) + (size_t)t * H_ + j] = hn;
                if (t == S_ - 1) out[(size_t)(B_ * S_ * H_) + idx] = hn;
            }
            publish(myfh, t + 1, lane);
        }
    }
}

extern "C" void kernel_launch(void* const* d_in, const int* in_sizes, int n_in,
                              void* d_out, int out_size, void* d_ws, size_t ws_size,
                              hipStream_t stream) {
    const float* x  = (const float*)d_in[0];
    const float* h0 = (const float*)d_in[1];
    const float* Wz = (const float*)d_in[2];
    const float* bz = (const float*)d_in[3];
    const float* Uz = (const float*)d_in[4];
    const float* Wr = (const float*)d_in[5];
    const float* br = (const float*)d_in[6];
    const float* Ur = (const float*)d_in[7];
    const float* Wh = (const float*)d_in[8];
    const float* bh = (const float*)d_in[9];
    const float* Uh = (const float*)d_in[10];
    float* out = (float*)d_out;

    const int WI = H_ * I_;                  // 524288 elems per W
    const int UU = H_ * H_;                  // 1048576 elems per U
    const size_t XN = (size_t)B_ * S_ * I_;  // 16777216 elems

    // ws layout: h_f32 | h_bf16[2] | rh | flags[512] | Wz Wr Wh (bf16) | Uz Ur Uh (bf16) | [x_b]
    char* w = (char*)d_ws;
    float* h_f32 = (float*)w;            w += (size_t)HB_ * 4;
    short* h_b   = (short*)w;            w += (size_t)HB_ * 2 * 2;   // double buffer
    short* rhb   = (short*)w;            w += (size_t)HB_ * 2;
    int*   flags = (int*)w;              w += 512 * 4;
    short* Wzb   = (short*)w;            w += (size_t)WI * 2;
    short* Wrb   = (short*)w;            w += (size_t)WI * 2;
    short* Whb   = (short*)w;            w += (size_t)WI * 2;
    short* Uzb   = (short*)w;            w += (size_t)UU * 2;
    short* Urb   = (short*)w;            w += (size_t)UU * 2;
    short* Uhb   = (short*)w;            w += (size_t)UU * 2;
    size_t base_need = (size_t)(w - (char*)d_ws);
    bool XB = ws_size >= base_need + XN * 2;
    short* xb = (short*)w;

    int* flagh = flags;          // [4][64]
    int* flagr = flags + 256;    // [4][64]

    gru_init<<<dim3(HB_ / 256), 256, 0, stream>>>(h0, h_f32, h_b, flags);
    cvt8k<<<dim3(WI / 8 / 256), 256, 0, stream>>>(Wz, Wzb, WI / 8);
    cvt8k<<<dim3(WI / 8 / 256), 256, 0, stream>>>(Wr, Wrb, WI / 8);
    cvt8k<<<dim3(WI / 8 / 256), 256, 0, stream>>>(Wh, Whb, WI / 8);
    cvt8k<<<dim3(UU / 8 / 256), 256, 0, stream>>>(Uz, Uzb, UU / 8);
    cvt8k<<<dim3(UU / 8 / 256), 256, 0, stream>>>(Ur, Urb, UU / 8);
    cvt8k<<<dim3(UU / 8 / 256), 256, 0, stream>>>(Uh, Uhb, UU / 8);
    if (XB)
        cvt8k<<<dim3((int)(XN / 8 / 256)), 256, 0, stream>>>(x, xb, (int)(XN / 8));

    if (XB)
        gru_persist<true><<<dim3(512), 64, 0, stream>>>(
            x, xb, h0, Wzb, bz, Uzb, Wrb, br, Urb, Whb, bh, Uhb,
            h_f32, h_b, rhb, flagh, flagr, out);
    else
        gru_persist<false><<<dim3(512), 64, 0, stream>>>(
            x, xb, h0, Wzb, bz, Uzb, Wrb, br, Urb, Whb, bh, Uhb,
            h_f32, h_b, rhb, flagh, flagr, out);
}